// Round 4
// baseline (77.723 us; speedup 1.0000x reference)
//
#include <hip/hip_runtime.h>
#include <math.h>

#define DD      4096
#define WW      129                 // 2*S+1 shifts
#define XSN     4240                // 64 left pad + 4096 + 80 right pad (1060 float4)
#define BLOCKN  256
#define NBLK    512                 // 4 blocks per (b,c) pair

// Partials + completion counter in module-scope device memory (NOT d_ws, so
// harness poison never touches them). g_cnt invariant: 0 at entry of every
// call; each of the 512 blocks adds 1; the last (old==511) runs the final
// reduction and resets it to 0. Release/acquire at agent scope makes the
// partials visible across XCDs.
__device__ float g_part[NBLK];
__device__ int   g_cnt = 0;

// One block per (b,c,p). Unrotated padded xh in LDS; wave wv computes shift
// group g = p + 4*wv (block p=0,wv=0 also g=16): 8 shifts per group via a
// 12-float sliding window from 3 contiguous ds_read_b128. y held in regs in
// the compute layout from the start; x regs reused between pass1 and pass2.
__global__ __launch_bounds__(BLOCKN) void spl_fused(
        const float* __restrict__ x, const float* __restrict__ y,
        float* __restrict__ out) {
    const int blk = blockIdx.x;           // 0 .. 511
    const int bc  = blk >> 2, p = blk & 3;
    const int b   = bc >> 1,  c = bc & 1;
    // jnp.flip(x, axis=1), C=2: output channel c <- x channel 1-c
    const float* xp = x + (size_t)(b * 2 + (1 - c)) * DD;
    const float* yp = y + (size_t)(b * 2 + c) * DD;
    const float4* xp4 = (const float4*)xp;
    const float4* yp4 = (const float4*)yp;

    __shared__ __align__(16) float xs[XSN];   // padded, unrotated xh
    __shared__ float P0s[65], P0q[65], Qs[65], Qq[65];
    __shared__ float red[16];
    __shared__ float wred[4];
    __shared__ int lastFlag;

    const int tid = threadIdx.x, lane = tid & 63, wv = tid >> 6;

    // zero pads: float4 idx [0,16) and [1040,1060) — disjoint from xh region
    if (tid < 36) {
        int i4 = (tid < 16) ? tid : (1024 + tid);
        ((float4*)xs)[i4] = make_float4(0.f, 0.f, 0.f, 0.f);
    }

    // ---- issue ALL global loads up front ----
    float4 xv4[4];                         // tid-layout: x[4*(tid+256*it)..]
    #pragma unroll
    for (int it = 0; it < 4; ++it) xv4[it] = xp4[tid + 256 * it];
    float4 yv4[16];                        // wave-layout: y[256*i + 4*lane..]
    #pragma unroll
    for (int i = 0; i < 16; ++i) yv4[i] = yp4[64 * i + lane];

    // ---- hann values for pass2 (no dependencies — hoisted) ----
    float4 h4[4];
    #pragma unroll
    for (int it = 0; it < 4; ++it) {
        float fd = (float)(4 * (tid + 256 * it));
        h4[it].x = 0.5f - 0.5f * __builtin_amdgcn_cosf((fd + 0.0f) * (1.0f / (float)DD));
        h4[it].y = 0.5f - 0.5f * __builtin_amdgcn_cosf((fd + 1.0f) * (1.0f / (float)DD));
        h4[it].z = 0.5f - 0.5f * __builtin_amdgcn_cosf((fd + 2.0f) * (1.0f / (float)DD));
        h4[it].w = 0.5f - 0.5f * __builtin_amdgcn_cosf((fd + 3.0f) * (1.0f / (float)DD));
    }

    // ---- x min/max (cross-wave) ----
    float xmn = 3.0e38f, xmx = -3.0e38f;
    #pragma unroll
    for (int it = 0; it < 4; ++it) {
        float4 xv = xv4[it];
        xmn = fminf(xmn, fminf(fminf(xv.x, xv.y), fminf(xv.z, xv.w)));
        xmx = fmaxf(xmx, fmaxf(fmaxf(xv.x, xv.y), fmaxf(xv.z, xv.w)));
    }
    #pragma unroll
    for (int off = 32; off > 0; off >>= 1) {
        xmn = fminf(xmn, __shfl_down(xmn, off, 64));
        xmx = fmaxf(xmx, __shfl_down(xmx, off, 64));
    }
    if (lane == 0) { red[wv] = xmn; red[4 + wv] = xmx; }

    // ---- y sum: per-wave (each wave holds the full row) ----
    float ys0 = 0.0f, ys1 = 0.0f;
    #pragma unroll
    for (int i = 0; i < 16; i += 2) {
        ys0 += (yv4[i].x + yv4[i].y) + (yv4[i].z + yv4[i].w);
        ys1 += (yv4[i + 1].x + yv4[i + 1].y) + (yv4[i + 1].z + yv4[i + 1].w);
    }
    float ysum = ys0 + ys1;
    #pragma unroll
    for (int off = 32; off > 0; off >>= 1) ysum += __shfl_down(ysum, off, 64);
    ysum = __shfl(ysum, 0, 64);
    const float ymean = ysum * (1.0f / (float)DD);

    __syncthreads();
    xmn = fminf(fminf(red[0], red[1]), fminf(red[2], red[3]));
    xmx = fmaxf(fmaxf(red[4], red[5]), fmaxf(red[6], red[7]));
    const float a   = 2.0f / (xmx - xmn);
    const float bsh = -a * xmn - 1.0f;

    // ---- pass2: xh = (a*x+bsh)*hann -> xs[64+d] (from regs, ds_write_b128) ----
    float ssum = 0.0f, ssq = 0.0f;
    #pragma unroll
    for (int it = 0; it < 4; ++it) {
        int i4 = tid + 256 * it;
        float4 v;
        v.x = fmaf(a, xv4[it].x, bsh) * h4[it].x;
        v.y = fmaf(a, xv4[it].y, bsh) * h4[it].y;
        v.z = fmaf(a, xv4[it].z, bsh) * h4[it].z;
        v.w = fmaf(a, xv4[it].w, bsh) * h4[it].w;
        ((float4*)(xs + 64))[i4] = v;
        ssum += (v.x + v.y) + (v.z + v.w);
        ssq = fmaf(v.x, v.x, fmaf(v.y, v.y, fmaf(v.z, v.z, fmaf(v.w, v.w, ssq))));
    }
    #pragma unroll
    for (int off = 32; off > 0; off >>= 1) {
        ssum += __shfl_down(ssum, off, 64);
        ssq  += __shfl_down(ssq,  off, 64);
    }
    if (lane == 0) { red[8 + wv] = ssum; red[12 + wv] = ssq; }

    // ---- center y in regs; syy per-wave ----
    float sy0 = 0.0f, sy1 = 0.0f;
    #pragma unroll
    for (int i = 0; i < 16; ++i) {
        yv4[i].x -= ymean; yv4[i].y -= ymean; yv4[i].z -= ymean; yv4[i].w -= ymean;
        float* acc = (i & 1) ? &sy1 : &sy0;
        *acc = fmaf(yv4[i].x, yv4[i].x, fmaf(yv4[i].y, yv4[i].y,
               fmaf(yv4[i].z, yv4[i].z, fmaf(yv4[i].w, yv4[i].w, *acc))));
    }
    float syy = sy0 + sy1;
    #pragma unroll
    for (int off = 32; off > 0; off >>= 1) syy += __shfl_down(syy, off, 64);
    syy = __shfl(syy, 0, 64);

    // ---- edge prefix scans (recompute xh at edges; L1-hot scalar loads) ----
    if (wv == 0) {                        // head: xh[0..63]
        int d = lane;
        float h = 0.5f - 0.5f * __builtin_amdgcn_cosf((float)d * (1.0f / (float)DD));
        float v = fmaf(a, xp[d], bsh) * h;
        float s = v, sq = v * v;
        #pragma unroll
        for (int off = 1; off < 64; off <<= 1) {
            float t  = __shfl_up(s,  off, 64);
            float tq = __shfl_up(sq, off, 64);
            if (lane >= off) { s += t; sq += tq; }
        }
        P0s[lane + 1] = s; P0q[lane + 1] = sq;
        if (lane == 0) { P0s[0] = 0.0f; P0q[0] = 0.0f; }
    } else if (wv == 1) {                 // tail: xh[4032..4095]
        int d = 4032 + lane;
        float h = 0.5f - 0.5f * __builtin_amdgcn_cosf((float)d * (1.0f / (float)DD));
        float v = fmaf(a, xp[d], bsh) * h;
        float s = v, sq = v * v;
        #pragma unroll
        for (int off = 1; off < 64; off <<= 1) {
            float t  = __shfl_up(s,  off, 64);
            float tq = __shfl_up(sq, off, 64);
            if (lane >= off) { s += t; sq += tq; }
        }
        float Ts = __shfl(s, 63, 64), Tq = __shfl(sq, 63, 64);
        Qs[lane] = Ts - (s - v);          // sum over l >= lane
        Qq[lane] = Tq - (sq - v * v);
        if (lane == 63) { Qs[64] = 0.0f; Qq[64] = 0.0f; }
    }
    __syncthreads();
    const float Stot  = (red[8]  + red[9])  + (red[10] + red[11]);
    const float Sqtot = (red[12] + red[13]) + (red[14] + red[15]);

    // ---- compute: groups of 8 shifts via 12-float sliding window ----
    const float4* xs4 = (const float4*)xs;
    float vmax = -3.0e38f;
    for (int g = p + 4 * wv; g <= 16; g += 16) {   // 1 group/wave (+1 once)
        float cr[8];
        #pragma unroll
        for (int j = 0; j < 8; ++j) cr[j] = 0.0f;
        const int A0 = lane + 2 * g;
        #pragma unroll
        for (int i = 0; i < 16; ++i) {
            int A = 64 * i + A0;
            float4 x0 = xs4[A], x1 = xs4[A + 1], x2 = xs4[A + 2];
            float wnd[12] = { x0.x, x0.y, x0.z, x0.w,
                              x1.x, x1.y, x1.z, x1.w,
                              x2.x, x2.y, x2.z, x2.w };
            float4 yv = yv4[i];
            #pragma unroll
            for (int j = 0; j < 8; ++j)
                cr[j] = fmaf(yv.x, wnd[j],
                        fmaf(yv.y, wnd[j + 1],
                        fmaf(yv.z, wnd[j + 2],
                        fmaf(yv.w, wnd[j + 3], cr[j]))));
        }
        #pragma unroll
        for (int off = 32; off > 0; off >>= 1) {
            #pragma unroll
            for (int j = 0; j < 8; ++j) cr[j] += __shfl_down(cr[j], off, 64);
        }
        if (lane == 0) {
            #pragma unroll
            for (int j = 0; j < 8; ++j) {
                int w = 8 * g + j;
                if (w < WW) {
                    int hidx = (w > 64) ? (w - 64) : 0;
                    int tidx = (w < 64) ? w : 64;
                    float sx   = Stot  - P0s[hidx] - Qs[tidx];
                    float sxx  = Sqtot - P0q[hidx] - Qq[tidx];
                    float varx = sxx - sx * sx * (1.0f / (float)DD);
                    float corr = cr[j] / sqrtf(varx * syy);
                    vmax = fmaxf(vmax, corr);
                }
            }
        }
    }
    if (lane == 0) wred[wv] = vmax;
    __syncthreads();

    // ---- publish partial; last block finishes ----
    if (tid == 0) {
        float bm = fmaxf(fmaxf(wred[0], wred[1]), fmaxf(wred[2], wred[3]));
        __hip_atomic_store(&g_part[blk], bm, __ATOMIC_RELEASE,
                           __HIP_MEMORY_SCOPE_AGENT);
        int old = __hip_atomic_fetch_add(&g_cnt, 1, __ATOMIC_ACQ_REL,
                                         __HIP_MEMORY_SCOPE_AGENT);
        lastFlag = (old == NBLK - 1) ? 1 : 0;
    }
    __syncthreads();
    if (lastFlag != 0 && wv == 0) {
        // values[b][c] = max over 4 partials; scores[b]=sqrt(v0^2+v1^2)
        const int bb = lane;
        float v0 = -3.0e38f, v1 = -3.0e38f;
        #pragma unroll
        for (int pp = 0; pp < 4; ++pp) {
            v0 = fmaxf(v0, __hip_atomic_load(&g_part[(bb * 2 + 0) * 4 + pp],
                            __ATOMIC_RELAXED, __HIP_MEMORY_SCOPE_AGENT));
            v1 = fmaxf(v1, __hip_atomic_load(&g_part[(bb * 2 + 1) * 4 + pp],
                            __ATOMIC_RELAXED, __HIP_MEMORY_SCOPE_AGENT));
        }
        float s = sqrtf(v0 * v0 + v1 * v1);
        #pragma unroll
        for (int off = 32; off > 0; off >>= 1) s += __shfl_down(s, off, 64);
        if (lane == 0) {
            out[0] = -s * (1.0f / 64.0f);
            __hip_atomic_store(&g_cnt, 0, __ATOMIC_RELAXED,
                               __HIP_MEMORY_SCOPE_AGENT);   // restore invariant
        }
    }
}

extern "C" void kernel_launch(void* const* d_in, const int* in_sizes, int n_in,
                              void* d_out, int out_size, void* d_ws, size_t ws_size,
                              hipStream_t stream) {
    const float* x = (const float*)d_in[0];
    const float* y = (const float*)d_in[1];
    float* out     = (float*)d_out;
    (void)d_ws; (void)ws_size;

    spl_fused<<<dim3(NBLK), dim3(BLOCKN), 0, stream>>>(x, y, out);
}

// Round 5
// 68.475 us; speedup vs baseline: 1.1351x; 1.1351x over previous
//
#include <hip/hip_runtime.h>
#include <math.h>

#define DD      4096
#define WW      129                 // 2*S+1 shifts
#define XSN     4240                // 64 left pad + 4096 + 80 right pad (1060 float4)
#define NP      4                   // blocks per (b,c) pair
#define BLOCKN  256

// One block per (b,c,p). Unrotated padded xh in LDS; wave wv computes shift
// group g = p + 4*wv (block p=0,wv=0 also g=16): 8 shifts per group via a
// 12-float sliding window from 3 contiguous ds_read_b128. x loaded once
// (regs reused by staging pass); y loaded once, directly in compute layout.
__global__ __launch_bounds__(BLOCKN) void spl_main(
        const float* __restrict__ x, const float* __restrict__ y,
        float* __restrict__ partial) {
    const int blk = blockIdx.x;           // 0 .. 128*NP-1
    const int bc  = blk >> 2, p = blk & 3;
    const int b   = bc >> 1,  c = bc & 1;
    // jnp.flip(x, axis=1), C=2: output channel c <- x channel 1-c
    const float* xp = x + (size_t)(b * 2 + (1 - c)) * DD;
    const float* yp = y + (size_t)(b * 2 + c) * DD;
    const float4* xp4 = (const float4*)xp;
    const float4* yp4 = (const float4*)yp;

    __shared__ __align__(16) float xs[XSN];   // padded, unrotated xh
    __shared__ float P0s[65], P0q[65], Qs[65], Qq[65];
    __shared__ float red[16];
    __shared__ float wred[4];

    const int tid = threadIdx.x, lane = tid & 63, wv = tid >> 6;

    // zero pads: float4 idx [0,16) and [1040,1060) — disjoint from xh region
    if (tid < 36) {
        int i4 = (tid < 16) ? tid : (1024 + tid);
        ((float4*)xs)[i4] = make_float4(0.f, 0.f, 0.f, 0.f);
    }

    // ---- issue ALL global loads up front (x once, y once) ----
    float4 xv4[4];                         // tid-layout: x[4*(tid+256*it)..]
    #pragma unroll
    for (int it = 0; it < 4; ++it) xv4[it] = xp4[tid + 256 * it];
    float4 yv4[16];                        // wave-layout: y[256*i + 4*lane..]
    #pragma unroll
    for (int i = 0; i < 16; ++i) yv4[i] = yp4[64 * i + lane];

    // ---- x min/max (cross-wave) ----
    float xmn = 3.0e38f, xmx = -3.0e38f;
    #pragma unroll
    for (int it = 0; it < 4; ++it) {
        float4 xv = xv4[it];
        xmn = fminf(xmn, fminf(fminf(xv.x, xv.y), fminf(xv.z, xv.w)));
        xmx = fmaxf(xmx, fmaxf(fmaxf(xv.x, xv.y), fmaxf(xv.z, xv.w)));
    }
    #pragma unroll
    for (int off = 32; off > 0; off >>= 1) {
        xmn = fminf(xmn, __shfl_down(xmn, off, 64));
        xmx = fmaxf(xmx, __shfl_down(xmx, off, 64));
    }
    if (lane == 0) { red[wv] = xmn; red[4 + wv] = xmx; }

    // ---- y sum: per-wave (each wave holds the full row) ----
    float ys0 = 0.0f, ys1 = 0.0f;
    #pragma unroll
    for (int i = 0; i < 16; i += 2) {
        ys0 += (yv4[i].x + yv4[i].y) + (yv4[i].z + yv4[i].w);
        ys1 += (yv4[i + 1].x + yv4[i + 1].y) + (yv4[i + 1].z + yv4[i + 1].w);
    }
    float ysum = ys0 + ys1;
    #pragma unroll
    for (int off = 32; off > 0; off >>= 1) ysum += __shfl_down(ysum, off, 64);
    ysum = __shfl(ysum, 0, 64);
    const float ymean = ysum * (1.0f / (float)DD);

    __syncthreads();
    xmn = fminf(fminf(red[0], red[1]), fminf(red[2], red[3]));
    xmx = fmaxf(fmaxf(red[4], red[5]), fmaxf(red[6], red[7]));
    const float a   = 2.0f / (xmx - xmn);
    const float bsh = -a * xmn - 1.0f;

    // ---- pass2: xh = (a*x+bsh)*hann -> xs[64+d] (from regs, hann inline) ----
    float ssum = 0.0f, ssq = 0.0f;
    #pragma unroll
    for (int it = 0; it < 4; ++it) {
        int i4 = tid + 256 * it;
        float fd = (float)(4 * i4);
        float4 v;
        v.x = fmaf(a, xv4[it].x, bsh) *
              (0.5f - 0.5f * __builtin_amdgcn_cosf((fd + 0.0f) * (1.0f / (float)DD)));
        v.y = fmaf(a, xv4[it].y, bsh) *
              (0.5f - 0.5f * __builtin_amdgcn_cosf((fd + 1.0f) * (1.0f / (float)DD)));
        v.z = fmaf(a, xv4[it].z, bsh) *
              (0.5f - 0.5f * __builtin_amdgcn_cosf((fd + 2.0f) * (1.0f / (float)DD)));
        v.w = fmaf(a, xv4[it].w, bsh) *
              (0.5f - 0.5f * __builtin_amdgcn_cosf((fd + 3.0f) * (1.0f / (float)DD)));
        ((float4*)(xs + 64))[i4] = v;
        ssum += (v.x + v.y) + (v.z + v.w);
        ssq = fmaf(v.x, v.x, fmaf(v.y, v.y, fmaf(v.z, v.z, fmaf(v.w, v.w, ssq))));
    }
    #pragma unroll
    for (int off = 32; off > 0; off >>= 1) {
        ssum += __shfl_down(ssum, off, 64);
        ssq  += __shfl_down(ssq,  off, 64);
    }
    if (lane == 0) { red[8 + wv] = ssum; red[12 + wv] = ssq; }

    // ---- center y in regs; syy per-wave ----
    float sy0 = 0.0f, sy1 = 0.0f;
    #pragma unroll
    for (int i = 0; i < 16; ++i) {
        yv4[i].x -= ymean; yv4[i].y -= ymean; yv4[i].z -= ymean; yv4[i].w -= ymean;
        float* acc = (i & 1) ? &sy1 : &sy0;
        *acc = fmaf(yv4[i].x, yv4[i].x, fmaf(yv4[i].y, yv4[i].y,
               fmaf(yv4[i].z, yv4[i].z, fmaf(yv4[i].w, yv4[i].w, *acc))));
    }
    float syy = sy0 + sy1;
    #pragma unroll
    for (int off = 32; off > 0; off >>= 1) syy += __shfl_down(syy, off, 64);
    syy = __shfl(syy, 0, 64);

    // ---- edge prefix scans (recompute xh at edges; L1-hot scalar loads) ----
    if (wv == 0) {                        // head: xh[0..63]
        int d = lane;
        float h = 0.5f - 0.5f * __builtin_amdgcn_cosf((float)d * (1.0f / (float)DD));
        float v = fmaf(a, xp[d], bsh) * h;
        float s = v, sq = v * v;
        #pragma unroll
        for (int off = 1; off < 64; off <<= 1) {
            float t  = __shfl_up(s,  off, 64);
            float tq = __shfl_up(sq, off, 64);
            if (lane >= off) { s += t; sq += tq; }
        }
        P0s[lane + 1] = s; P0q[lane + 1] = sq;
        if (lane == 0) { P0s[0] = 0.0f; P0q[0] = 0.0f; }
    } else if (wv == 1) {                 // tail: xh[4032..4095]
        int d = 4032 + lane;
        float h = 0.5f - 0.5f * __builtin_amdgcn_cosf((float)d * (1.0f / (float)DD));
        float v = fmaf(a, xp[d], bsh) * h;
        float s = v, sq = v * v;
        #pragma unroll
        for (int off = 1; off < 64; off <<= 1) {
            float t  = __shfl_up(s,  off, 64);
            float tq = __shfl_up(sq, off, 64);
            if (lane >= off) { s += t; sq += tq; }
        }
        float Ts = __shfl(s, 63, 64), Tq = __shfl(sq, 63, 64);
        Qs[lane] = Ts - (s - v);          // sum over l >= lane
        Qq[lane] = Tq - (sq - v * v);
        if (lane == 63) { Qs[64] = 0.0f; Qq[64] = 0.0f; }
    }
    __syncthreads();
    const float Stot  = (red[8]  + red[9])  + (red[10] + red[11]);
    const float Sqtot = (red[12] + red[13]) + (red[14] + red[15]);

    // ---- compute: groups of 8 shifts via 12-float sliding window ----
    const float4* xs4 = (const float4*)xs;
    float vmax = -3.0e38f;
    for (int g = p + 4 * wv; g <= 16; g += 16) {   // 1 group/wave (+1 once)
        float cr[8];
        #pragma unroll
        for (int j = 0; j < 8; ++j) cr[j] = 0.0f;
        const int A0 = lane + 2 * g;
        #pragma unroll
        for (int i = 0; i < 16; ++i) {
            int A = 64 * i + A0;
            float4 x0 = xs4[A], x1 = xs4[A + 1], x2 = xs4[A + 2];
            float wnd[12] = { x0.x, x0.y, x0.z, x0.w,
                              x1.x, x1.y, x1.z, x1.w,
                              x2.x, x2.y, x2.z, x2.w };
            float4 yv = yv4[i];
            #pragma unroll
            for (int j = 0; j < 8; ++j)
                cr[j] = fmaf(yv.x, wnd[j],
                        fmaf(yv.y, wnd[j + 1],
                        fmaf(yv.z, wnd[j + 2],
                        fmaf(yv.w, wnd[j + 3], cr[j]))));
        }
        #pragma unroll
        for (int off = 32; off > 0; off >>= 1) {
            #pragma unroll
            for (int j = 0; j < 8; ++j) cr[j] += __shfl_down(cr[j], off, 64);
        }
        if (lane == 0) {
            #pragma unroll
            for (int j = 0; j < 8; ++j) {
                int w = 8 * g + j;
                if (w < WW) {
                    int hidx = (w > 64) ? (w - 64) : 0;
                    int tidx = (w < 64) ? w : 64;
                    float sx   = Stot  - P0s[hidx] - Qs[tidx];
                    float sxx  = Sqtot - P0q[hidx] - Qq[tidx];
                    float varx = sxx - sx * sx * (1.0f / (float)DD);
                    float corr = cr[j] / sqrtf(varx * syy);
                    vmax = fmaxf(vmax, corr);
                }
            }
        }
    }
    if (lane == 0) wred[wv] = vmax;
    __syncthreads();
    if (tid == 0)
        partial[blk] = fmaxf(fmaxf(wred[0], wred[1]), fmaxf(wred[2], wred[3]));
}

// values[b][c] = max over NP partials; scores[b] = sqrt(v0^2+v1^2);
// out = -mean(scores)
__global__ void spl_final(const float* __restrict__ partial,
                          float* __restrict__ out) {
    const int b = threadIdx.x;   // 64 threads, one per batch row
    float v0 = -3.0e38f, v1 = -3.0e38f;
    #pragma unroll
    for (int pp = 0; pp < NP; ++pp) {
        v0 = fmaxf(v0, partial[(b * 2 + 0) * NP + pp]);
        v1 = fmaxf(v1, partial[(b * 2 + 1) * NP + pp]);
    }
    float s = sqrtf(v0 * v0 + v1 * v1);
    #pragma unroll
    for (int off = 32; off > 0; off >>= 1) s += __shfl_down(s, off, 64);
    if (b == 0) out[0] = -s * (1.0f / 64.0f);
}

extern "C" void kernel_launch(void* const* d_in, const int* in_sizes, int n_in,
                              void* d_out, int out_size, void* d_ws, size_t ws_size,
                              hipStream_t stream) {
    const float* x = (const float*)d_in[0];
    const float* y = (const float*)d_in[1];
    float* out     = (float*)d_out;
    float* partial = (float*)d_ws;   // 128*NP floats = 2 KB

    spl_main<<<dim3(128 * NP), dim3(BLOCKN), 0, stream>>>(x, y, partial);
    spl_final<<<dim3(1), dim3(64), 0, stream>>>(partial, out);
}